// Round 15
// baseline (200.829 us; speedup 1.0000x reference)
//
#include <hip/hip_runtime.h>

#define NPTS 16384
#define DIM 256
#define NKC 32                 // k-chunks of 8 halfs: pure data, no augmentation
#define KNN 5
#define RPB 256                // rows per block = 8 waves x 32
#define CTILE 64               // candidates per tile
#define STRIPS 8
#define STRIP (NPTS / STRIPS)  // 2048
#define NCB (STRIP / CTILE)    // 32
#define TOPS 7                 // per-strip shortlist depth (self + 5 + 1 spare)
#define SLW (STRIPS * TOPS)    // 56 shortlist slots per row
#define SEL 8                  // candidates rescored exactly per row
#define NRB (NPTS / 4)         // rescore blocks (4 rows each) = 4096

typedef _Float16 f16x8 __attribute__((ext_vector_type(8)));
typedef float    f32x4 __attribute__((ext_vector_type(4)));

// workspace byte offsets
#define WS_NORMS 4096                          // float [NPTS]
#define WS_HIA   (WS_NORMS + NPTS * 4)         // _Float16 [NKC][NPTS][8] k-major
#define WS_SL    (WS_HIA + NPTS * NKC * 16)    // unsigned [NPTS][SLW]
#define WS_PART  (WS_SL + NPTS * SLW * 4)      // int [NRB] per-block match counts

// pack positive fp16 score + 14-bit idx into one sortable u32
__device__ __forceinline__ unsigned packsi(float s, int idx) {
    union { _Float16 h; unsigned short u; } cv;
    cv.h = (_Float16)s;                       // RNE, score > 0 by construction
    return ((unsigned)cv.u << 16) | (unsigned)idx;
}

__device__ __forceinline__ unsigned umed3(unsigned a, unsigned b, unsigned c) {
    unsigned d;
    asm("v_med3_u32 %0, %1, %2, %3" : "=v"(d) : "v"(a), "v"(b), "v"(c));
    return d;
}

// compare-exchange (min/max) on packed u32 — 2 VALU ops, idx travels free
#define CEU(a, b) do {                                                        \
    unsigned mn_ = (a) < (b) ? (a) : (b);                                     \
    unsigned mx_ = (a) < (b) ? (b) : (a);                                     \
    (a) = mn_; (b) = mx_;                                                     \
} while (0)

// med3 sorted-insert into ascending TOPS-list (identical result to min/max
// bubble, 7 ops instead of 14): L'[0]=min(L0,x); L'[e]=med3(x, L[e], oldL[e-1])
#define BUBBLE_U(Lp, x) do {                                                  \
    unsigned c_ = (x);                                                        \
    unsigned po_ = Lp[0];                                                     \
    Lp[0] = c_ < po_ ? c_ : po_;                                              \
    _Pragma("unroll")                                                         \
    for (int e_ = 1; e_ < TOPS; ++e_) {                                       \
        unsigned cur_ = Lp[e_];                                               \
        Lp[e_] = umed3(c_, cur_, po_);                                        \
        po_ = cur_;                                                           \
    } } while (0)

// K0: k-major fp16 buffer hiA[kc][row][8] = -2*fp16(row); fp32 norms.
__global__ __launch_bounds__(256) void prep_kernel(const float* __restrict__ emb,
                                                   float* __restrict__ norms,
                                                   _Float16* __restrict__ hiA) {
    const int row = blockIdx.x * 4 + (threadIdx.x >> 6);
    const int l   = threadIdx.x & 63;
    float4 v = *reinterpret_cast<const float4*>(emb + (size_t)row * DIM + l * 4);
    union { _Float16 h[4]; short4 s; } u;
    u.h[0] = (_Float16)v.x * (_Float16)-2.0f;
    u.h[1] = (_Float16)v.y * (_Float16)-2.0f;
    u.h[2] = (_Float16)v.z * (_Float16)-2.0f;
    u.h[3] = (_Float16)v.w * (_Float16)-2.0f;
    *reinterpret_cast<short4*>(hiA + ((size_t)(l >> 1) * NPTS + row) * 8 + (l & 1) * 4) = u.s;

    float s = v.x * v.x + v.y * v.y + v.z * v.z + v.w * v.w;
#pragma unroll
    for (int off = 32; off > 0; off >>= 1) s += __shfl_down(s, off, 64);
    if (l == 0) norms[row] = s;
}

// K1: MFMA filter, K=256 (no aug). score = (||c||^2+512) + (-2 q.c) added in
// the epilogue from an LDS norm table; packed-u32 screen; cf-major pipeline
// with deferred EPI3; double-buffered At with counted vmcnt.
__global__ __launch_bounds__(512, 4) void filter_kernel(const _Float16* __restrict__ hiA,
                                                        const float* __restrict__ norms,
                                                        unsigned* __restrict__ shortlist) {
    __shared__ _Float16 At[2 * NKC * CTILE * 8];   // 65536 B
    __shared__ float    nLds[STRIP];               // 8192 B: strip norms + 512
    const int tid  = threadIdx.x;
    const int w    = tid >> 6;        // wave 0..7
    const int l    = tid & 63;
    const int lq16 = l & 15;          // D col = query-row-in-16
    const int lk4  = l >> 4;          // k-quarter / cand sub-group
    const int panel = blockIdx.x >> 3;
    const int strip = blockIdx.x & 7; // native XCD slot -> strip slice L2-resident
    const int qbase = panel * RPB;
    const int cand0 = strip * STRIP;
    const int rot   = panel & (NCB - 1);   // phase-decorrelated tile start

    // ---- stage strip norms (+512 positivity bias) into LDS, once ----
    {
        float4 nv = *reinterpret_cast<const float4*>(norms + cand0 + tid * 4);
        nv.x += 512.0f; nv.y += 512.0f; nv.z += 512.0f; nv.w += 512.0f;
        *reinterpret_cast<float4*>(nLds + tid * 4) = nv;
    }
    asm volatile("s_waitcnt lgkmcnt(0)" ::: "memory");   // writes land pre-barrier

    // ---- B fragments resident: 2 rf x 8 t (kc = t*4+lk4), coalesced loads ----
    const size_t r0 = (size_t)qbase + w * 32 + lq16;
    f16x8 breg0[8], breg1[8];
#pragma unroll
    for (int t = 0; t < 8; ++t) {
        f16x8 v0 = *reinterpret_cast<const f16x8*>(hiA + ((size_t)(t * 4 + lk4) * NPTS + r0) * 8);
        f16x8 v1 = *reinterpret_cast<const f16x8*>(hiA + ((size_t)(t * 4 + lk4) * NPTS + r0 + 16) * 8);
#pragma unroll
        for (int e = 0; e < 8; ++e) {   // -0.5 * (-2q) = q, exact in fp16
            v0[e] = v0[e] * (_Float16)-0.5f;
            v1[e] = v1[e] * (_Float16)-0.5f;
        }
        breg0[t] = v0; breg1[t] = v1;
    }

    // ascending sorted top-7, packed u32
    unsigned Lp0[TOPS], Lp1[TOPS];
#pragma unroll
    for (int e = 0; e < TOPS; ++e) { Lp0[e] = 0xFFFFFFFFu; Lp1[e] = 0xFFFFFFFFu; }

    // uniform staging: 4 x 16B per thread = 32 KB tile
#define STAGE(bufoff, tt) do {                                                \
    const int cbn_ = cand0 + (tt) * CTILE;                                    \
    _Pragma("unroll")                                                         \
    for (int i_ = 0; i_ < 4; ++i_) {                                          \
        int d_ = i_ * 8192 + tid * 16;                                        \
        int kc_ = d_ >> 10, cd_ = (d_ >> 4) & 63;                             \
        const _Float16* g_ = hiA + ((size_t)kc_ * NPTS + cbn_ + cd_) * 8;     \
        __builtin_amdgcn_global_load_lds(                                     \
            (const __attribute__((address_space(1))) void*)g_,                \
            (__attribute__((address_space(3))) void*)((char*)At + (bufoff) + d_), 16, 0, 0); \
    } } while (0)

// MFMA burst for candidate column cf: 8 k-steps x 2 rf (t ascending per acc)
#define MFMA_CF(cf) do {                                                      \
    _Pragma("unroll")                                                         \
    for (int t_ = 0; t_ < 8; ++t_) {                                          \
        f16x8 af_ = *reinterpret_cast<const f16x8*>(                          \
            Ab + (size_t)((t_ * 4 + lk4) * 64 + (cf) * 16 + lq16) * 16);      \
        acc0[cf] = __builtin_amdgcn_mfma_f32_16x16x32_f16(af_, breg0[t_], acc0[cf], 0, 0, 0); \
        acc1[cf] = __builtin_amdgcn_mfma_f32_16x16x32_f16(af_, breg1[t_], acc1[cf], 0, 0, 0); \
    } } while (0)

// epilogue for column cf: score = acc + (||c||^2+512); pack -> 4-CEU -> med3
#define EPI_CF(cf, cbx, nbv) do {                                             \
    const int c0_ = (cbx) + (cf) * 16 + (lk4 << 2);                           \
    {                                                                         \
        unsigned p0 = packsi(acc0[cf][0] + (nbv).x, c0_ + 0);                 \
        unsigned p1 = packsi(acc0[cf][1] + (nbv).y, c0_ + 1);                 \
        unsigned p2 = packsi(acc0[cf][2] + (nbv).z, c0_ + 2);                 \
        unsigned p3 = packsi(acc0[cf][3] + (nbv).w, c0_ + 3);                 \
        CEU(p0, p1); CEU(p2, p3); CEU(p0, p2); CEU(p1, p2);                   \
        BUBBLE_U(Lp0, p0);                                                    \
        BUBBLE_U(Lp0, p1);                                                    \
        unsigned m23 = p2 < p3 ? p2 : p3;                                     \
        if (__any(m23 < Lp0[TOPS - 1])) { BUBBLE_U(Lp0, p2); BUBBLE_U(Lp0, p3); } \
    }                                                                         \
    {                                                                         \
        unsigned p0 = packsi(acc1[cf][0] + (nbv).x, c0_ + 0);                 \
        unsigned p1 = packsi(acc1[cf][1] + (nbv).y, c0_ + 1);                 \
        unsigned p2 = packsi(acc1[cf][2] + (nbv).z, c0_ + 2);                 \
        unsigned p3 = packsi(acc1[cf][3] + (nbv).w, c0_ + 3);                 \
        CEU(p0, p1); CEU(p2, p3); CEU(p0, p2); CEU(p1, p2);                   \
        BUBBLE_U(Lp1, p0);                                                    \
        BUBBLE_U(Lp1, p1);                                                    \
        unsigned m23 = p2 < p3 ? p2 : p3;                                     \
        if (__any(m23 < Lp1[TOPS - 1])) { BUBBLE_U(Lp1, p2); BUBBLE_U(Lp1, p3); } \
    } } while (0)

    STAGE(0, rot);

    int buf = 0;
    int cbase_prev = 0;
    float4 nb3p = make_float4(0.f, 0.f, 0.f, 0.f);
    f32x4 acc0[4], acc1[4];    // hoisted: acc[3] survives across the barrier
    for (int cb = 0; cb < NCB; ++cb) {
        const int t_cur = (cb + rot) & (NCB - 1);
        // issue next-tile loads, then wait ONLY for the current tile's loads
        if (cb + 1 < NCB) {
            STAGE((buf ^ 1) * 32768, (cb + 1 + rot) & (NCB - 1));
            asm volatile("s_waitcnt vmcnt(4)" ::: "memory");
        } else {
            asm volatile("s_waitcnt vmcnt(0)" ::: "memory");
        }
        __builtin_amdgcn_sched_barrier(0);
        __builtin_amdgcn_s_barrier();      // all waves: current buf fully landed
        __builtin_amdgcn_sched_barrier(0);

        const char* Ab = (const char*)At + buf * 32768;
        const int cbase = cand0 + t_cur * CTILE;
        const float* nrow = nLds + t_cur * CTILE + (lk4 << 2);
        float4 nbv0 = *reinterpret_cast<const float4*>(nrow);
        float4 nbv1 = *reinterpret_cast<const float4*>(nrow + 16);
        float4 nbv2 = *reinterpret_cast<const float4*>(nrow + 32);
        float4 nbv3 = *reinterpret_cast<const float4*>(nrow + 48);
#pragma unroll
        for (int cf = 0; cf < 3; ++cf) {   // acc[3] init deferred until EPI3(prev) ran
            acc0[cf] = (f32x4){0.f, 0.f, 0.f, 0.f};
            acc1[cf] = (f32x4){0.f, 0.f, 0.f, 0.f};
        }

        // cf-major pipeline; deferred EPI3(prev) overlaps this tile's MFMA
        __builtin_amdgcn_s_setprio(1);
        MFMA_CF(0);
        if (cb > 0) { EPI_CF(3, cbase_prev, nb3p); }
        acc0[3] = (f32x4){0.f, 0.f, 0.f, 0.f};
        acc1[3] = (f32x4){0.f, 0.f, 0.f, 0.f};
        MFMA_CF(1); EPI_CF(0, cbase, nbv0);
        MFMA_CF(2); EPI_CF(1, cbase, nbv1);
        MFMA_CF(3); EPI_CF(2, cbase, nbv2);
        __builtin_amdgcn_s_setprio(0);

        // fence buf reuse: LDS reads complete, then barrier (NO vmcnt drain)
        asm volatile("s_waitcnt lgkmcnt(0)" ::: "memory");
        __builtin_amdgcn_sched_barrier(0);
        __builtin_amdgcn_s_barrier();
        __builtin_amdgcn_sched_barrier(0);
        cbase_prev = cbase;
        nb3p = nbv3;
        buf ^= 1;
    }
    EPI_CF(3, cbase_prev, nb3p);   // peeled: last tile's column-3 epilogue
#undef STAGE
#undef MFMA_CF
#undef EPI_CF

    // ---- merge the 4 cand-partitions per row (snapshot butterfly over lk4) ----
#pragma unroll
    for (int mask = 16; mask <= 32; mask <<= 1) {
        unsigned pd[TOPS];
#pragma unroll
        for (int e = 0; e < TOPS; ++e)
            pd[e] = (unsigned)__shfl_xor((int)Lp0[e], mask, 64);
#pragma unroll
        for (int e = 0; e < TOPS; ++e) BUBBLE_U(Lp0, pd[e]);
#pragma unroll
        for (int e = 0; e < TOPS; ++e)
            pd[e] = (unsigned)__shfl_xor((int)Lp1[e], mask, 64);
#pragma unroll
        for (int e = 0; e < TOPS; ++e) BUBBLE_U(Lp1, pd[e]);
    }

    if (lk4 == 0) {   // lanes 0..15: final per-strip packed top-7 for both rows
        unsigned* dst0 = shortlist + r0 * SLW + strip * TOPS;
        unsigned* dst1 = shortlist + (r0 + 16) * SLW + strip * TOPS;
#pragma unroll
        for (int e = 0; e < TOPS; ++e) { dst0[e] = Lp0[e]; dst1[e] = Lp1[e]; }
    }
}

// K2: per row (one wave): bitonic-sort the 56 packed survivors across lanes,
// take the 8 lex-smallest, gather + exact fp32 rescore (8 lanes/cand),
// exact (dist, idx) lexicographic top-5, label match; partials slot (no atomic).
__global__ __launch_bounds__(256) void rescore_kernel(const float* __restrict__ emb,
                                                      const int* __restrict__ labels,
                                                      const float* __restrict__ norms,
                                                      const unsigned* __restrict__ shortlist,
                                                      int* __restrict__ partials) {
    __shared__ float qrow[4][DIM];
    __shared__ int   pc[4];
    const int tid = threadIdx.x;
    const int w = tid >> 6, l = tid & 63;
    const int q = blockIdx.x * 4 + w;

    *reinterpret_cast<float4*>(&qrow[w][l * 4]) =
        *reinterpret_cast<const float4*>(emb + (size_t)q * DIM + l * 4);

    unsigned v = 0xFFFFFFFFu;
    if (l < SLW) v = shortlist[(size_t)q * SLW + l];
    __syncthreads();

    // 64-lane bitonic sort ascending (packed u32; 8 pad lanes sort last)
#pragma unroll
    for (int k = 2; k <= 64; k <<= 1) {
#pragma unroll
        for (int j = k >> 1; j > 0; j >>= 1) {
            unsigned o = (unsigned)__shfl_xor((int)v, j, 64);
            bool keepmin = (((l & j) == 0) == ((l & k) == 0));
            unsigned mn = v < o ? v : o;
            unsigned mx = v < o ? o : v;
            v = keepmin ? mn : mx;
        }
    }

    const int cslot = l >> 3, part = l & 7;       // 8 cands x 8 lanes
    unsigned sel = (unsigned)__shfl((int)v, cslot, 64);
    int ci = (int)(sel & 0xFFFFu);

    float dv = 3.0e38f; int civ = 0x7fffffff;
    {
        const float* crow = emb + (size_t)ci * DIM + part * 32;   // 32 dims/lane
        const float* qr = &qrow[w][part * 32];
        float p0 = 0.f, p1 = 0.f, p2 = 0.f, p3 = 0.f;
#pragma unroll
        for (int kk = 0; kk < 8; ++kk) {
            float4 cv4 = *reinterpret_cast<const float4*>(crow + kk * 4);
            float4 qv4 = *reinterpret_cast<const float4*>(qr + kk * 4);
            p0 = fmaf(cv4.x, qv4.x, p0); p1 = fmaf(cv4.y, qv4.y, p1);
            p2 = fmaf(cv4.z, qv4.z, p2); p3 = fmaf(cv4.w, qv4.w, p3);
        }
        float p = (p0 + p1) + (p2 + p3);
        p += __shfl_xor(p, 1, 64);
        p += __shfl_xor(p, 2, 64);
        p += __shfl_xor(p, 4, 64);
        if (part == 0 && ci != q) { dv = fmaf(-2.0f, p, norms[q] + norms[ci]); civ = ci; }
    }

    // relocate the 8 (dist,idx) to every 8-lane coset: lane reads lane (l&7)*8
    float dv2 = __shfl(dv, (l & 7) * 8, 64);
    int  civ2 = __shfl(civ, (l & 7) * 8, 64);

    const int lq = labels[q];
    bool match = false;
#pragma unroll
    for (int r = 0; r < KNN; ++r) {
        float md = dv2; int mxi = civ2;
#pragma unroll
        for (int mask = 1; mask <= 4; mask <<= 1) {
            float pd = __shfl_xor(md, mask, 64);
            int   pi = __shfl_xor(mxi, mask, 64);
            if (pd < md || (pd == md && pi < mxi)) { md = pd; mxi = pi; }
        }
        if (civ2 == mxi) dv2 = 3.0e38f;   // owner copy retires in every coset
        match = match || (labels[mxi] == lq);
    }
    if (l == 0) pc[w] = match ? 1 : 0;
    __syncthreads();
    if (tid == 0) partials[blockIdx.x] = pc[0] + pc[1] + pc[2] + pc[3];
}

// K3: tree-reduce the 4096 per-block partials; out = sum / N (exact pow2 div)
__global__ __launch_bounds__(1024) void finalize_kernel(const int* __restrict__ partials,
                                                        float* __restrict__ out) {
    __shared__ int ws[16];
    const int tid = threadIdx.x;
    int4 v = *reinterpret_cast<const int4*>(partials + tid * 4);
    int s = v.x + v.y + v.z + v.w;
#pragma unroll
    for (int off = 32; off > 0; off >>= 1) s += __shfl_down(s, off, 64);
    if ((tid & 63) == 0) ws[tid >> 6] = s;
    __syncthreads();
    if (tid < 16) {
        int t = ws[tid];
#pragma unroll
        for (int off = 8; off > 0; off >>= 1) t += __shfl_down(t, off, 64);
        if (tid == 0) out[0] = (float)t * (1.0f / (float)NPTS);
    }
}

extern "C" void kernel_launch(void* const* d_in, const int* in_sizes, int n_in,
                              void* d_out, int out_size, void* d_ws, size_t ws_size,
                              hipStream_t stream) {
    (void)in_sizes; (void)n_in; (void)out_size; (void)ws_size;
    const float* emb    = (const float*)d_in[0];
    const int*   labels = (const int*)d_in[1];
    float*       out    = (float*)d_out;

    char* ws = (char*)d_ws;
    float*     norms     = (float*)(ws + WS_NORMS);
    _Float16*  hiA       = (_Float16*)(ws + WS_HIA);
    unsigned*  shortlist = (unsigned*)(ws + WS_SL);
    int*       partials  = (int*)(ws + WS_PART);

    prep_kernel<<<NPTS / 4, 256, 0, stream>>>(emb, norms, hiA);
    filter_kernel<<<(NPTS / RPB) * STRIPS, 512, 0, stream>>>(hiA, norms, shortlist);
    rescore_kernel<<<NRB, 256, 0, stream>>>(emb, labels, norms, shortlist, partials);
    finalize_kernel<<<1, 1024, 0, stream>>>(partials, out);
}

// Round 16
// 196.141 us; speedup vs baseline: 1.0239x; 1.0239x over previous
//
#include <hip/hip_runtime.h>

#define NPTS 16384
#define DIM 256
#define NKC 36                 // augmented kchunks: 32 data + [hc,lc] + [1,1,2] + 2 pad
#define KNN 5
#define RPB 256                // rows per block = 8 waves x 32
#define CTILE 64               // candidates per tile
#define STRIPS 8
#define STRIP (NPTS / STRIPS)  // 2048
#define NCB (STRIP / CTILE)    // 32
#define TOPS 7                 // per-strip shortlist depth (self + 5 + 1 spare)
#define SLW (STRIPS * TOPS)    // 56 shortlist slots per row
#define SEL 8                  // candidates rescored exactly per row
#define NRB (NPTS / 4)         // rescore blocks (4 rows each) = 4096

typedef _Float16 f16x8 __attribute__((ext_vector_type(8)));
typedef float    f32x4 __attribute__((ext_vector_type(4)));

// workspace byte offsets
#define WS_NORMS 4096                          // float [NPTS]
#define WS_HIA   (WS_NORMS + NPTS * 4)         // _Float16 [NKC][NPTS][8] k-major
#define WS_SL    (WS_HIA + NPTS * NKC * 16)    // unsigned [NPTS][SLW]
#define WS_PART  (WS_SL + NPTS * SLW * 4)      // int [NRB] per-block match counts

// pack positive fp16 score + 14-bit idx into one sortable u32
__device__ __forceinline__ unsigned packsi(float s, int idx) {
    union { _Float16 h; unsigned short u; } cv;
    cv.h = (_Float16)s;                       // RNE, score > 0 by construction
    return ((unsigned)cv.u << 16) | (unsigned)idx;
}

__device__ __forceinline__ unsigned umed3(unsigned a, unsigned b, unsigned c) {
    unsigned d;
    asm("v_med3_u32 %0, %1, %2, %3" : "=v"(d) : "v"(a), "v"(b), "v"(c));
    return d;
}

// compare-exchange (min/max) on packed u32 — 2 VALU ops, idx travels free
#define CEU(a, b) do {                                                        \
    unsigned mn_ = (a) < (b) ? (a) : (b);                                     \
    unsigned mx_ = (a) < (b) ? (b) : (a);                                     \
    (a) = mn_; (b) = mx_;                                                     \
} while (0)

// med3 sorted-insert into ascending TOPS-list (identical result to min/max
// bubble, 7 ops instead of 14): L'[0]=min(L0,x); L'[e]=med3(x, L[e], oldL[e-1])
#define BUBBLE_U(Lp, x) do {                                                  \
    unsigned c_ = (x);                                                        \
    unsigned po_ = Lp[0];                                                     \
    Lp[0] = c_ < po_ ? c_ : po_;                                              \
    _Pragma("unroll")                                                         \
    for (int e_ = 1; e_ < TOPS; ++e_) {                                       \
        unsigned cur_ = Lp[e_];                                               \
        Lp[e_] = umed3(c_, cur_, po_);                                        \
        po_ = cur_;                                                           \
    } } while (0)

// K0: k-major augmented fp16 buffer hiA[kc][row][8]:
// kc 0..31 = -2*fp16(row), kc32 = [h,l,0..] (h+l ~= ||row||^2),
// kc33 = [1,1,2,0..] (constant), kc34/35 = 0. Plus fp32 norms.
__global__ __launch_bounds__(256) void prep_kernel(const float* __restrict__ emb,
                                                   float* __restrict__ norms,
                                                   _Float16* __restrict__ hiA) {
    const int row = blockIdx.x * 4 + (threadIdx.x >> 6);
    const int l   = threadIdx.x & 63;
    float4 v = *reinterpret_cast<const float4*>(emb + (size_t)row * DIM + l * 4);
    union { _Float16 h[4]; short4 s; } u;
    u.h[0] = (_Float16)v.x * (_Float16)-2.0f;
    u.h[1] = (_Float16)v.y * (_Float16)-2.0f;
    u.h[2] = (_Float16)v.z * (_Float16)-2.0f;
    u.h[3] = (_Float16)v.w * (_Float16)-2.0f;
    *reinterpret_cast<short4*>(hiA + ((size_t)(l >> 1) * NPTS + row) * 8 + (l & 1) * 4) = u.s;

    float s = v.x * v.x + v.y * v.y + v.z * v.z + v.w * v.w;
#pragma unroll
    for (int off = 32; off > 0; off >>= 1) s += __shfl_down(s, off, 64);
    float tot = __shfl(s, 0, 64);
    if (l == 0) norms[row] = tot;
    if (l < 4) {   // chunks 32..35
        union { _Float16 h[4]; short4 s; } z0, z1;
        z0.h[0] = (_Float16)0.f; z0.h[1] = (_Float16)0.f;
        z0.h[2] = (_Float16)0.f; z0.h[3] = (_Float16)0.f;
        z1 = z0;
        if (l == 0) {
            _Float16 hh = (_Float16)tot;
            _Float16 ll = (_Float16)(tot - (float)hh);
            z0.h[0] = hh; z0.h[1] = ll;
        }
        if (l == 1) {   // A-side of the +||q||^2+4 fold
            z0.h[0] = (_Float16)1.0f; z0.h[1] = (_Float16)1.0f; z0.h[2] = (_Float16)2.0f;
        }
        _Float16* dst = hiA + ((size_t)(32 + l) * NPTS + row) * 8;
        *reinterpret_cast<short4*>(dst)     = z0.s;
        *reinterpret_cast<short4*>(dst + 4) = z1.s;
    }
}

// K1: MFMA filter — cf-major pipelined; EPI of column 3 deferred into the next
// tile's MFMA burst (acc hoisted above the loop; peeled EPI3 after the loop).
__global__ __launch_bounds__(512, 4) void filter_kernel(const _Float16* __restrict__ hiA,
                                                        unsigned* __restrict__ shortlist) {
    __shared__ _Float16 At[2 * NKC * CTILE * 8];   // 73728 B
    const int tid  = threadIdx.x;
    const int w    = tid >> 6;        // wave 0..7
    const int l    = tid & 63;
    const int lq16 = l & 15;          // D col = query-row-in-16
    const int lk4  = l >> 4;          // k-quarter / cand sub-group
    const int panel = blockIdx.x >> 3;
    const int strip = blockIdx.x & 7; // native XCD slot -> strip slice L2-resident
    const int qbase = panel * RPB;
    const int cand0 = strip * STRIP;
    const int rot   = panel & (NCB - 1);   // phase-decorrelated tile start

    // ---- B fragments resident: 2 rf x 8 t (kc = t*4+lk4), coalesced loads ----
    const size_t r0 = (size_t)qbase + w * 32 + lq16;
    f16x8 breg0[8], breg1[8];
#pragma unroll
    for (int t = 0; t < 8; ++t) {
        f16x8 v0 = *reinterpret_cast<const f16x8*>(hiA + ((size_t)(t * 4 + lk4) * NPTS + r0) * 8);
        f16x8 v1 = *reinterpret_cast<const f16x8*>(hiA + ((size_t)(t * 4 + lk4) * NPTS + r0 + 16) * 8);
#pragma unroll
        for (int e = 0; e < 8; ++e) {   // -0.5 * (-2q) = q, exact in fp16
            v0[e] = v0[e] * (_Float16)-0.5f;
            v1[e] = v1[e] * (_Float16)-0.5f;
        }
        breg0[t] = v0; breg1[t] = v1;
    }
    // augmented k-step (t=8): lk4=0 -> [1,1,0..] (picks hc+lc);
    // lk4=1 -> [hq,lq,2,0..] (picks hq+lq+4 against A's [1,1,2]); else 0.
    f16x8 b8_0 = 0, b8_1 = 0;
    {
        f16x8 raw0 = *reinterpret_cast<const f16x8*>(hiA + ((size_t)32 * NPTS + r0) * 8);
        f16x8 raw1 = *reinterpret_cast<const f16x8*>(hiA + ((size_t)32 * NPTS + r0 + 16) * 8);
        if (lk4 == 0) {
            b8_0[0] = (_Float16)1.0f; b8_0[1] = (_Float16)1.0f;
            b8_1[0] = (_Float16)1.0f; b8_1[1] = (_Float16)1.0f;
        } else if (lk4 == 1) {
            b8_0 = raw0; b8_0[2] = (_Float16)2.0f;
            b8_1 = raw1; b8_1[2] = (_Float16)2.0f;
        }
    }

    // ascending sorted top-7, packed u32
    unsigned Lp0[TOPS], Lp1[TOPS];
#pragma unroll
    for (int e = 0; e < TOPS; ++e) { Lp0[e] = 0xFFFFFFFFu; Lp1[e] = 0xFFFFFFFFu; }

    // waves 0..3 issue 5 loads per STAGE; waves 4..7 issue 4 (wave-uniform split)
#define STAGE(bufoff, tt) do {                                                \
    const int cbn_ = cand0 + (tt) * CTILE;                                    \
    _Pragma("unroll")                                                         \
    for (int i_ = 0; i_ < 4; ++i_) {                                          \
        int d_ = i_ * 8192 + tid * 16;                                        \
        int kc_ = d_ >> 10, cd_ = (d_ >> 4) & 63;                             \
        const _Float16* g_ = hiA + ((size_t)kc_ * NPTS + cbn_ + cd_) * 8;     \
        __builtin_amdgcn_global_load_lds(                                     \
            (const __attribute__((address_space(1))) void*)g_,                \
            (__attribute__((address_space(3))) void*)((char*)At + (bufoff) + d_), 16, 0, 0); \
    }                                                                         \
    if (tid < 256) {                                                          \
        int d_ = 32768 + tid * 16;                                            \
        int kc_ = d_ >> 10, cd_ = (d_ >> 4) & 63;                             \
        const _Float16* g_ = hiA + ((size_t)kc_ * NPTS + cbn_ + cd_) * 8;     \
        __builtin_amdgcn_global_load_lds(                                     \
            (const __attribute__((address_space(1))) void*)g_,                \
            (__attribute__((address_space(3))) void*)((char*)At + (bufoff) + d_), 16, 0, 0); \
    } } while (0)

// MFMA burst for candidate column cf: 9 k-steps x 2 rf (t ascending per acc)
#define MFMA_CF(cf) do {                                                      \
    _Pragma("unroll")                                                         \
    for (int t_ = 0; t_ < 9; ++t_) {                                          \
        f16x8 bf0_ = (t_ < 8) ? breg0[t_] : b8_0;                             \
        f16x8 bf1_ = (t_ < 8) ? breg1[t_] : b8_1;                             \
        f16x8 af_ = *reinterpret_cast<const f16x8*>(                          \
            Ab + (size_t)((t_ * 4 + lk4) * 64 + (cf) * 16 + lq16) * 16);      \
        acc0[cf] = __builtin_amdgcn_mfma_f32_16x16x32_f16(af_, bf0_, acc0[cf], 0, 0, 0); \
        acc1[cf] = __builtin_amdgcn_mfma_f32_16x16x32_f16(af_, bf1_, acc1[cf], 0, 0, 0); \
    } } while (0)

// epilogue for column cf against base cbx: pack -> 4-CEU -> med3 bubbles
#define EPI_CF(cf, cbx) do {                                                  \
    const int c0_ = (cbx) + (cf) * 16 + (lk4 << 2);                           \
    {                                                                         \
        unsigned p0 = packsi(acc0[cf][0], c0_ + 0);                           \
        unsigned p1 = packsi(acc0[cf][1], c0_ + 1);                           \
        unsigned p2 = packsi(acc0[cf][2], c0_ + 2);                           \
        unsigned p3 = packsi(acc0[cf][3], c0_ + 3);                           \
        CEU(p0, p1); CEU(p2, p3); CEU(p0, p2); CEU(p1, p2);                   \
        BUBBLE_U(Lp0, p0);                                                    \
        BUBBLE_U(Lp0, p1);                                                    \
        unsigned m23 = p2 < p3 ? p2 : p3;                                     \
        if (__any(m23 < Lp0[TOPS - 1])) { BUBBLE_U(Lp0, p2); BUBBLE_U(Lp0, p3); } \
    }                                                                         \
    {                                                                         \
        unsigned p0 = packsi(acc1[cf][0], c0_ + 0);                           \
        unsigned p1 = packsi(acc1[cf][1], c0_ + 1);                           \
        unsigned p2 = packsi(acc1[cf][2], c0_ + 2);                           \
        unsigned p3 = packsi(acc1[cf][3], c0_ + 3);                           \
        CEU(p0, p1); CEU(p2, p3); CEU(p0, p2); CEU(p1, p2);                   \
        BUBBLE_U(Lp1, p0);                                                    \
        BUBBLE_U(Lp1, p1);                                                    \
        unsigned m23 = p2 < p3 ? p2 : p3;                                     \
        if (__any(m23 < Lp1[TOPS - 1])) { BUBBLE_U(Lp1, p2); BUBBLE_U(Lp1, p3); } \
    } } while (0)

    STAGE(0, rot);

    int buf = 0;
    int cbase_prev = 0;
    f32x4 acc0[4], acc1[4];    // hoisted: acc[3] must survive across the barrier
    for (int cb = 0; cb < NCB; ++cb) {
        const int t_cur = (cb + rot) & (NCB - 1);
        // issue next-tile loads, then wait ONLY for the current tile's loads
        if (cb + 1 < NCB) {
            STAGE((buf ^ 1) * 36864, (cb + 1 + rot) & (NCB - 1));
            if (w < 4) { asm volatile("s_waitcnt vmcnt(9)" ::: "memory"); }
            else       { asm volatile("s_waitcnt vmcnt(8)" ::: "memory"); }
        } else {
            asm volatile("s_waitcnt vmcnt(0)" ::: "memory");
        }
        __builtin_amdgcn_sched_barrier(0);
        __builtin_amdgcn_s_barrier();      // all waves: current buf fully landed
        __builtin_amdgcn_sched_barrier(0);

        const char* Ab = (const char*)At + buf * 36864;
        const int cbase = cand0 + t_cur * CTILE;
#pragma unroll
        for (int cf = 0; cf < 3; ++cf) {   // acc[3] init deferred until EPI3(prev) ran
            acc0[cf] = (f32x4){0.f, 0.f, 0.f, 0.f};
            acc1[cf] = (f32x4){0.f, 0.f, 0.f, 0.f};
        }

        // cf-major pipeline; deferred EPI3(prev) overlaps this tile's MFMA
        __builtin_amdgcn_s_setprio(1);
        MFMA_CF(0);
        if (cb > 0) { EPI_CF(3, cbase_prev); }
        acc0[3] = (f32x4){0.f, 0.f, 0.f, 0.f};
        acc1[3] = (f32x4){0.f, 0.f, 0.f, 0.f};
        MFMA_CF(1); EPI_CF(0, cbase);
        MFMA_CF(2); EPI_CF(1, cbase);
        MFMA_CF(3); EPI_CF(2, cbase);
        __builtin_amdgcn_s_setprio(0);

        // fence buf reuse: LDS reads complete, then barrier (NO vmcnt drain)
        asm volatile("s_waitcnt lgkmcnt(0)" ::: "memory");
        __builtin_amdgcn_sched_barrier(0);
        __builtin_amdgcn_s_barrier();
        __builtin_amdgcn_sched_barrier(0);
        cbase_prev = cbase;
        buf ^= 1;
    }
    EPI_CF(3, cbase_prev);   // peeled: last tile's column-3 epilogue
#undef STAGE
#undef MFMA_CF
#undef EPI_CF

    // ---- merge the 4 cand-partitions per row (snapshot butterfly over lk4) ----
#pragma unroll
    for (int mask = 16; mask <= 32; mask <<= 1) {
        unsigned pd[TOPS];
#pragma unroll
        for (int e = 0; e < TOPS; ++e)
            pd[e] = (unsigned)__shfl_xor((int)Lp0[e], mask, 64);
#pragma unroll
        for (int e = 0; e < TOPS; ++e) BUBBLE_U(Lp0, pd[e]);
#pragma unroll
        for (int e = 0; e < TOPS; ++e)
            pd[e] = (unsigned)__shfl_xor((int)Lp1[e], mask, 64);
#pragma unroll
        for (int e = 0; e < TOPS; ++e) BUBBLE_U(Lp1, pd[e]);
    }

    if (lk4 == 0) {   // lanes 0..15: final per-strip packed top-7 for both rows
        unsigned* dst0 = shortlist + r0 * SLW + strip * TOPS;
        unsigned* dst1 = shortlist + (r0 + 16) * SLW + strip * TOPS;
#pragma unroll
        for (int e = 0; e < TOPS; ++e) { dst0[e] = Lp0[e]; dst1[e] = Lp1[e]; }
    }
}

// K2: per row (one wave): bitonic-sort the 56 packed survivors across lanes,
// take the 8 lex-smallest, gather + exact fp32 rescore (8 lanes/cand),
// exact (dist, idx) lexicographic top-5, label match; partials slot (no atomic).
__global__ __launch_bounds__(256) void rescore_kernel(const float* __restrict__ emb,
                                                      const int* __restrict__ labels,
                                                      const float* __restrict__ norms,
                                                      const unsigned* __restrict__ shortlist,
                                                      int* __restrict__ partials) {
    __shared__ float qrow[4][DIM];
    __shared__ int   pc[4];
    const int tid = threadIdx.x;
    const int w = tid >> 6, l = tid & 63;
    const int q = blockIdx.x * 4 + w;

    *reinterpret_cast<float4*>(&qrow[w][l * 4]) =
        *reinterpret_cast<const float4*>(emb + (size_t)q * DIM + l * 4);

    unsigned v = 0xFFFFFFFFu;
    if (l < SLW) v = shortlist[(size_t)q * SLW + l];
    __syncthreads();

    // 64-lane bitonic sort ascending (packed u32; 8 pad lanes sort last)
#pragma unroll
    for (int k = 2; k <= 64; k <<= 1) {
#pragma unroll
        for (int j = k >> 1; j > 0; j >>= 1) {
            unsigned o = (unsigned)__shfl_xor((int)v, j, 64);
            bool keepmin = (((l & j) == 0) == ((l & k) == 0));
            unsigned mn = v < o ? v : o;
            unsigned mx = v < o ? o : v;
            v = keepmin ? mn : mx;
        }
    }

    const int cslot = l >> 3, part = l & 7;       // 8 cands x 8 lanes
    unsigned sel = (unsigned)__shfl((int)v, cslot, 64);
    int ci = (int)(sel & 0xFFFFu);

    float dv = 3.0e38f; int civ = 0x7fffffff;
    {
        const float* crow = emb + (size_t)ci * DIM + part * 32;   // 32 dims/lane
        const float* qr = &qrow[w][part * 32];
        float p0 = 0.f, p1 = 0.f, p2 = 0.f, p3 = 0.f;
#pragma unroll
        for (int kk = 0; kk < 8; ++kk) {
            float4 cv4 = *reinterpret_cast<const float4*>(crow + kk * 4);
            float4 qv4 = *reinterpret_cast<const float4*>(qr + kk * 4);
            p0 = fmaf(cv4.x, qv4.x, p0); p1 = fmaf(cv4.y, qv4.y, p1);
            p2 = fmaf(cv4.z, qv4.z, p2); p3 = fmaf(cv4.w, qv4.w, p3);
        }
        float p = (p0 + p1) + (p2 + p3);
        p += __shfl_xor(p, 1, 64);
        p += __shfl_xor(p, 2, 64);
        p += __shfl_xor(p, 4, 64);
        if (part == 0 && ci != q) { dv = fmaf(-2.0f, p, norms[q] + norms[ci]); civ = ci; }
    }

    // relocate the 8 (dist,idx) to every 8-lane coset: lane reads lane (l&7)*8
    float dv2 = __shfl(dv, (l & 7) * 8, 64);
    int  civ2 = __shfl(civ, (l & 7) * 8, 64);

    const int lq = labels[q];
    bool match = false;
#pragma unroll
    for (int r = 0; r < KNN; ++r) {
        float md = dv2; int mxi = civ2;
#pragma unroll
        for (int mask = 1; mask <= 4; mask <<= 1) {
            float pd = __shfl_xor(md, mask, 64);
            int   pi = __shfl_xor(mxi, mask, 64);
            if (pd < md || (pd == md && pi < mxi)) { md = pd; mxi = pi; }
        }
        if (civ2 == mxi) dv2 = 3.0e38f;   // owner copy retires in every coset
        match = match || (labels[mxi] == lq);
    }
    if (l == 0) pc[w] = match ? 1 : 0;
    __syncthreads();
    if (tid == 0) partials[blockIdx.x] = pc[0] + pc[1] + pc[2] + pc[3];
}

// K3: tree-reduce the 4096 per-block partials; out = sum / N (exact pow2 div)
__global__ __launch_bounds__(1024) void finalize_kernel(const int* __restrict__ partials,
                                                        float* __restrict__ out) {
    __shared__ int ws[16];
    const int tid = threadIdx.x;
    int4 v = *reinterpret_cast<const int4*>(partials + tid * 4);
    int s = v.x + v.y + v.z + v.w;
#pragma unroll
    for (int off = 32; off > 0; off >>= 1) s += __shfl_down(s, off, 64);
    if ((tid & 63) == 0) ws[tid >> 6] = s;
    __syncthreads();
    if (tid < 16) {
        int t = ws[tid];
#pragma unroll
        for (int off = 8; off > 0; off >>= 1) t += __shfl_down(t, off, 64);
        if (tid == 0) out[0] = (float)t * (1.0f / (float)NPTS);
    }
}

extern "C" void kernel_launch(void* const* d_in, const int* in_sizes, int n_in,
                              void* d_out, int out_size, void* d_ws, size_t ws_size,
                              hipStream_t stream) {
    (void)in_sizes; (void)n_in; (void)out_size; (void)ws_size;
    const float* emb    = (const float*)d_in[0];
    const int*   labels = (const int*)d_in[1];
    float*       out    = (float*)d_out;

    char* ws = (char*)d_ws;
    float*     norms     = (float*)(ws + WS_NORMS);
    _Float16*  hiA       = (_Float16*)(ws + WS_HIA);
    unsigned*  shortlist = (unsigned*)(ws + WS_SL);
    int*       partials  = (int*)(ws + WS_PART);

    prep_kernel<<<NPTS / 4, 256, 0, stream>>>(emb, norms, hiA);
    filter_kernel<<<(NPTS / RPB) * STRIPS, 512, 0, stream>>>(hiA, shortlist);
    rescore_kernel<<<NRB, 256, 0, stream>>>(emb, labels, norms, shortlist, partials);
    finalize_kernel<<<1, 1024, 0, stream>>>(partials, out);
}